// Round 1
// baseline (116.961 us; speedup 1.0000x reference)
//
#include <hip/hip_runtime.h>
#include <hip/hip_bf16.h>

// CARAFE fused: B=4, C=128, H=W=64, C_MID=64, S=2, K=5
// Round 11: finer decomposition for occupancy. 4x4 tiles -> 1024 blocks x 512
// threads = 8192 waves = 32 waves/CU (was 4096 waves = 16/CU = 50%).
// LDS cut to 30.5KB via hs/ks alias (barrier-separated lifetimes) -> 4 blocks/CU.
// __launch_bounds__(512,8) caps VGPR at 64; per-wave state halved (acc[8] in E).
#define HW 4096

typedef __attribute__((ext_vector_type(8))) short  short8;   // 8 bf16 (4 VGPRs)
typedef __attribute__((ext_vector_type(4))) float  floatx4;  // MFMA C/D

// workspace (BYTE offsets)
#define OFF_W2B 0ul        // bf16 [112][576]  = 129024 B   w2b[n][k], k = tap*64 + c
#define OFF_W1B 129024ul   // bf16 [64][128]   = 16384 B    w1b[o][c]
#define OFF_BN  145408ul   // float2[64]       = 512 B      (inv, add) per o
#define OFF_XG  145920ul   // bf16 [4][16][4096][8] = 4 MB  x transposed: [b][cq][pix][8c]

__device__ __forceinline__ float bfbits(unsigned u) {
    union { unsigned u; float f; } t; t.u = u; return t.f;
}

// ---------------- prep: x -> bf16 [b][cq][pix][8]; w2 -> bf16 [n][k]; w1 bf16; BN folded ----
__global__ __launch_bounds__(256) void prep_kernel(const float* __restrict__ x,
                                                   const float* __restrict__ w1,
                                                   const float* __restrict__ w2,
                                                   const float* __restrict__ gamma,
                                                   const float* __restrict__ beta,
                                                   const float* __restrict__ mean,
                                                   const float* __restrict__ var,
                                                   char* __restrict__ ws) {
    int tid = blockIdx.x * 256 + threadIdx.x;
    if (tid < 262144) {
        int pix = tid & 4095;
        int cq  = (tid >> 12) & 15;
        int b   = tid >> 16;
        const float* xp = x + ((size_t)(b * 128 + cq * 8)) * HW + pix;
        union { short8 s; __hip_bfloat16 h[8]; } u;
        #pragma unroll
        for (int cc = 0; cc < 8; ++cc) u.h[cc] = __float2bfloat16(xp[(size_t)cc * HW]);
        *(short8*)((__hip_bfloat16*)(ws + OFF_XG) + (size_t)tid * 8) = u.s;
        return;
    }
    int t2 = tid - 262144;
    if (t2 < 64512) {
        int n = t2 / 576;
        int k = t2 - n * 576;        // k = tap*64 + c
        int t = k >> 6, c = k & 63;
        float v = (n < 100) ? w2[(n * 64 + c) * 9 + t] : 0.f;
        ((__hip_bfloat16*)(ws + OFF_W2B))[t2] = __float2bfloat16(v);
    } else if (t2 < 64512 + 8192) {
        int i = t2 - 64512;
        ((__hip_bfloat16*)(ws + OFF_W1B))[i] = __float2bfloat16(w1[i]);
    } else if (t2 < 64512 + 8192 + 64) {
        int o = t2 - 64512 - 8192;
        float inv = gamma[o] * rsqrtf(var[o] + 1e-5f);
        ((float2*)(ws + OFF_BN))[o] = make_float2(inv, beta[o] - mean[o] * inv);
    }
}

// ---------------- fused CARAFE: one block per (b, 4x4 tile), 512 threads = 8 waves ----------
// LDS layout (aliased, 30480 B total):
//   xs [16 cq][64 pix][8 ch] bf16   @ 0      (16384 B)  pix = 8x8 halo, live A..E
//   lg [16 pix][114]       f32      @ 16384  ( 7296 B)  live C..D
//   hs [36 pix][72 ch]     bf16     @ 23680  ( 5184 B)  live B..C  } aliased
//   ks [100 tg][17 pix]    f32      @ 23680  ( 6800 B)  live D..E  } (barrier-separated)
__global__ __launch_bounds__(512, 8) void fused_carafe(const char* __restrict__ ws,
                                                       float* __restrict__ out) {
    __shared__ __align__(16) char smem[30480];
    __hip_bfloat16* xs = (__hip_bfloat16*)smem;
    float*          lg = (float*)(smem + 16384);
    __hip_bfloat16* hs = (__hip_bfloat16*)(smem + 23680);
    float*          ks = (float*)(smem + 23680);

    int b    = blockIdx.x >> 8;
    int tile = blockIdx.x & 255;
    int ty0 = (tile >> 4) * 4;
    int tx0 = (tile & 15) * 4;
    int tid = threadIdx.x;
    int lane = tid & 63, wave = tid >> 6;   // 8 waves
    int q = lane >> 4, m = lane & 15;

    // ---- phase A: copy x 8x8 halo (bf16, pre-transposed) -> xs, b128 in/out ----
    const __hip_bfloat16* xg = (const __hip_bfloat16*)(ws + OFF_XG) + (size_t)b * 16 * 4096 * 8;
    #pragma unroll
    for (int it = 0; it < 2; ++it) {
        int idx = tid + it * 512;             // 1024 = 16 cq * 64 pix
        int cq = idx >> 6, p = idx & 63;
        int gy = ty0 + (p >> 3) - 2, gx = tx0 + (p & 7) - 2;
        short8 v;
        #pragma unroll
        for (int j = 0; j < 8; ++j) v[j] = 0;
        if ((unsigned)gy < 64u && (unsigned)gx < 64u)
            v = *(const short8*)(xg + ((size_t)cq * 4096 + gy * 64 + gx) * 8);
        *(short8*)(xs + (size_t)idx * 8) = v;
    }
    __syncthreads();

    // ---- phase B: h = relu(bn(w1 @ x)) via MFMA: M=36 halo pix (6x6), N=64, K=128 ----
    // 12 tasks (3 mt x 4 nt) over 8 waves
    {
        const __hip_bfloat16* w1b = (const __hip_bfloat16*)(ws + OFF_W1B);
        for (int task = wave; task < 12; task += 8) {
            int mt = task >> 2, nt = task & 3;
            int bo = nt * 16 + m;
            float2 bnia = ((const float2*)(ws + OFF_BN))[bo];
            int hp = mt * 16 + m;
            int hpc = (hp < 36) ? hp : 0;          // clamp dead A-rows (C rows discarded)
            int hy1 = hpc / 6, hx1 = hpc - hy1 * 6;
            int xrow = (hy1 + 1) * 8 + (hx1 + 1);
            floatx4 acc;
            #pragma unroll
            for (int r = 0; r < 4; ++r) acc[r] = 0.f;
            #pragma unroll
            for (int s = 0; s < 4; ++s) {
                short8 a  = *(const short8*)(xs + ((size_t)(s * 4 + q) * 64 + xrow) * 8);
                short8 bw = *(const short8*)(w1b + bo * 128 + s * 32 + q * 8);
                acc = __builtin_amdgcn_mfma_f32_16x16x32_bf16(a, bw, acc, 0, 0, 0);
            }
            #pragma unroll
            for (int r = 0; r < 4; ++r) {
                int prow = mt * 16 + q * 4 + r;
                if (prow < 36) {
                    int phy = prow / 6, phx = prow - phy * 6;
                    int gy = ty0 + phy - 1, gx = tx0 + phx - 1;
                    bool in = ((unsigned)gy < 64u) && ((unsigned)gx < 64u);
                    float v = in ? fmaxf(fmaf(acc[r], bnia.x, bnia.y), 0.f) : 0.f;
                    hs[prow * 72 + bo] = __float2bfloat16(v);
                }
            }
        }
    }
    __syncthreads();

    // ---- phase C: 3x3 conv via MFMA: M=16 pix, N=112, K=576; 7 n-tile tasks ----
    if (wave < 7) {
        int nt = wave;
        int py = m >> 2, px = m & 3;
        const __hip_bfloat16* w2b = (const __hip_bfloat16*)(ws + OFF_W2B);
        const __hip_bfloat16* bp  = w2b + (size_t)(nt * 16 + m) * 576 + q * 8;

        floatx4 acc;
        #pragma unroll
        for (int r = 0; r < 4; ++r) acc[r] = 0.f;

        short8 bcur = *(const short8*)bp;
        for (int s = 0; s < 18; ++s) {
            int t = s >> 1, c0 = (s & 1) * 32;
            int ti = t / 3, tj = t - ti * 3;
            short8 a = *(const short8*)(hs + ((size_t)((py + ti) * 6 + px + tj)) * 72 + c0 + q * 8);
            short8 bn2 = bcur;
            if (s < 17) bn2 = *(const short8*)(bp + (s + 1) * 32);
            acc = __builtin_amdgcn_mfma_f32_16x16x32_bf16(a, bcur, acc, 0, 0, 0);
            bcur = bn2;
        }
        #pragma unroll
        for (int r = 0; r < 4; ++r)
            lg[(q * 4 + r) * 114 + nt * 16 + m] = acc[r];
    }
    __syncthreads();

    // ---- phase D: softmax over 25 taps -> ks [t*4+g][pix]; 64 softmaxes on wave 0 ----
    if (tid < 64) {
        int pix = tid & 15, g = tid >> 4;
        float v[25];
        #pragma unroll
        for (int wi = 0; wi < 25; ++wi) v[wi] = lg[pix * 114 + g * 25 + wi];
        float mx = v[0];
        #pragma unroll
        for (int wi = 1; wi < 25; ++wi) mx = fmaxf(mx, v[wi]);
        float ssum = 0.f;
        #pragma unroll
        for (int wi = 0; wi < 25; ++wi) { v[wi] = __expf(v[wi] - mx); ssum += v[wi]; }
        float rs = 1.f / ssum;
        #pragma unroll
        for (int t25 = 0; t25 < 25; ++t25)
            ks[(t25 * 4 + g) * 17 + pix] = v[t25] * rs;
    }
    __syncthreads();

    // ---- phase E: 5x5 reassembly + pixel shuffle; lane owns (pix, subpixel g) ----
    {
        int pix = lane & 15, g4 = lane >> 4;     // 16 pix x 4 subpixels = 64 lanes
        int py = pix >> 2, px = pix & 3;
        int Y = ty0 + py, X = tx0 + px;
        int gy = g4 >> 1, gx = g4 & 1;
        float* op = out + ((((size_t)b * 128) * 128 + (2 * Y + gy)) * 128 + 2 * X + gx);

        for (int co = wave; co < 16; co += 8) {
            float acc[8];
            #pragma unroll
            for (int i = 0; i < 8; ++i) acc[i] = 0.f;

            const __hip_bfloat16* xsb = xs + (size_t)co * 64 * 8;
            #pragma unroll 5
            for (int t = 0; t < 25; ++t) {
                int ti = t / 5, tj = t - ti * 5;
                int xrow = (py + ti) * 8 + (px + tj);
                union { short8 s; unsigned u[4]; } xv;
                xv.s = *(const short8*)(xsb + xrow * 8);   // broadcast across g-lanes
                float k = ks[(t * 4 + g4) * 17 + pix];
                #pragma unroll
                for (int j = 0; j < 4; ++j) {
                    float xa  = bfbits(xv.u[j] << 16);
                    float xb2 = bfbits(xv.u[j] & 0xFFFF0000u);
                    acc[j * 2 + 0] = fmaf(xa,  k, acc[j * 2 + 0]);
                    acc[j * 2 + 1] = fmaf(xb2, k, acc[j * 2 + 1]);
                }
            }

            #pragma unroll
            for (int i = 0; i < 8; ++i)
                op[(size_t)(co * 8 + i) << 14] = acc[i];   // 16384 floats per channel
        }
    }
}

extern "C" void kernel_launch(void* const* d_in, const int* in_sizes, int n_in,
                              void* d_out, int out_size, void* d_ws, size_t ws_size,
                              hipStream_t stream) {
    const float* x     = (const float*)d_in[0];
    const float* w1    = (const float*)d_in[1];
    const float* w2    = (const float*)d_in[2];
    const float* gamma = (const float*)d_in[3];
    const float* beta  = (const float*)d_in[4];
    const float* mean  = (const float*)d_in[5];
    const float* var   = (const float*)d_in[6];
    float* out = (float*)d_out;
    char*  ws  = (char*)d_ws;

    prep_kernel<<<1309, 256, 0, stream>>>(x, w1, w2, gamma, beta, mean, var, ws);
    fused_carafe<<<1024, 512, 0, stream>>>(ws, out);
}